// Round 2
// baseline (585.573 us; speedup 1.0000x reference)
//
#include <hip/hip_runtime.h>

// MultiHeadSelfAttention: X(4,512,512) -> QKV via fused conv projections,
// cross-head attention score (4,8,8,512,512) [output #2], ctx = P@V, out proj.
// All fp32 (CDNA4 has no fp32 MFMA; round 1 = correctness + clean structure).
// ws layout (floats): Q[1M] K[1M] V[1M] ctx_partial[8 x 1M]  => 46 MB total.

__device__ __forceinline__ void fma4(float4& a, float s, const float4& v) {
  a.x = fmaf(s, v.x, a.x);
  a.y = fmaf(s, v.y, a.y);
  a.z = fmaf(s, v.z, a.z);
  a.w = fmaf(s, v.w, a.w);
}

// ---------------------------------------------------------------------------
// Fused 2-layer conv projection: conv3x3(1->8)+BN+ReLU, conv3x3(8->1)+BN+ReLU.
// 32x32 output tile per block; y1 (34x34x8) lives in LDS only.
// y1 halo positions outside the 512x512 image are ZERO (reference zero-pads
// the intermediate tensor for the second SAME conv) — masked below.
// nparts==8: input is sum of 8 partial buffers (ctx reduction fused here).
// ---------------------------------------------------------------------------
__global__ __launch_bounds__(256)
void conv_proj_kernel(const float* __restrict__ in, int nparts,
                      float* __restrict__ out, int fixed_proj,
                      const float* __restrict__ w1, const float* __restrict__ b1,
                      const float* __restrict__ g1, const float* __restrict__ be1,
                      const float* __restrict__ m1, const float* __restrict__ v1,
                      const float* __restrict__ w2, const float* __restrict__ b2,
                      const float* __restrict__ g2, const float* __restrict__ be2,
                      const float* __restrict__ m2, const float* __restrict__ v2)
{
  __shared__ float xs[36][36];
  __shared__ float ys[8][34][34];
  __shared__ float w1s[8][9];
  __shared__ float w2s[8][9];
  __shared__ float a1s[8], c1s[8];
  __shared__ float a2s[1], c2s[1];

  const int t = threadIdx.x;
  int proj, b;
  if (fixed_proj < 0) { proj = blockIdx.z >> 2; b = blockIdx.z & 3; }
  else                { proj = fixed_proj;      b = blockIdx.z;     }
  const int h0 = blockIdx.y * 32;
  const int w0 = blockIdx.x * 32;

  if (t < 72) {
    w1s[t / 9][t % 9] = w1[proj * 72 + t];
    w2s[t / 9][t % 9] = w2[proj * 72 + t];
  } else if (t < 80) {
    int ch = t - 72;
    float a = g1[proj * 8 + ch] * rsqrtf(v1[proj * 8 + ch] + 1e-5f);
    a1s[ch] = a;
    c1s[ch] = fmaf(a, b1[proj * 8 + ch] - m1[proj * 8 + ch], be1[proj * 8 + ch]);
  } else if (t == 80) {
    float a = g2[proj] * rsqrtf(v2[proj] + 1e-5f);
    a2s[0] = a;
    c2s[0] = fmaf(a, b2[proj] - m2[proj], be2[proj]);
  }

  // Stage 36x36 input tile (halo 2, zero-padded SAME).
  for (int idx = t; idx < 36 * 36; idx += 256) {
    int r = idx / 36, c = idx - r * 36;
    int hg = h0 - 2 + r, wg = w0 - 2 + c;
    float val = 0.f;
    if (hg >= 0 && hg < 512 && wg >= 0 && wg < 512) {
      int off = b * 262144 + hg * 512 + wg;
      if (nparts == 1) {
        val = in[off];
      } else {
        #pragma unroll
        for (int p = 0; p < 8; ++p) val += in[p * 1048576 + off];
      }
    }
    xs[r][c] = val;
  }
  __syncthreads();

  // Layer 1: y1 (34x34 positions x 8 channels). Zero outside the image:
  // the reference's second conv zero-pads y1, so halo rows/cols at global
  // -1 / 512 must be exactly 0, not conv-of-partial-window.
  for (int idx = t; idx < 34 * 34; idx += 256) {
    int r = idx / 34, c = idx - r * 34;
    int hg1 = h0 - 1 + r, wg1 = w0 - 1 + c;
    bool inside = (hg1 >= 0) & (hg1 < 512) & (wg1 >= 0) & (wg1 < 512);
    float x0 = xs[r    ][c], x1 = xs[r    ][c + 1], x2 = xs[r    ][c + 2];
    float x3 = xs[r + 1][c], x4 = xs[r + 1][c + 1], x5 = xs[r + 1][c + 2];
    float x6 = xs[r + 2][c], x7 = xs[r + 2][c + 1], x8 = xs[r + 2][c + 2];
    #pragma unroll
    for (int ch = 0; ch < 8; ++ch) {
      const float* w = w1s[ch];
      float acc = w[0] * x0 + w[1] * x1 + w[2] * x2
                + w[3] * x3 + w[4] * x4 + w[5] * x5
                + w[6] * x6 + w[7] * x7 + w[8] * x8;
      float y = fmaxf(fmaf(acc, a1s[ch], c1s[ch]), 0.f);
      ys[ch][r][c] = inside ? y : 0.f;
    }
  }
  __syncthreads();

  // Layer 2: each thread computes a 2x2 output block (register-cached 4x4 window).
  const int r0 = (t >> 4) * 2;
  const int c0 = (t & 15) * 2;
  float o00 = 0.f, o01 = 0.f, o10 = 0.f, o11 = 0.f;
  #pragma unroll
  for (int ch = 0; ch < 8; ++ch) {
    float win[4][4];
    #pragma unroll
    for (int rr = 0; rr < 4; ++rr) {
      float2 p0 = *(const float2*)&ys[ch][r0 + rr][c0];
      float2 p1 = *(const float2*)&ys[ch][r0 + rr][c0 + 2];
      win[rr][0] = p0.x; win[rr][1] = p0.y; win[rr][2] = p1.x; win[rr][3] = p1.y;
    }
    #pragma unroll
    for (int dh = 0; dh < 3; ++dh)
      #pragma unroll
      for (int dw = 0; dw < 3; ++dw) {
        float wgt = w2s[ch][dh * 3 + dw];
        o00 = fmaf(wgt, win[dh    ][dw    ], o00);
        o01 = fmaf(wgt, win[dh    ][dw + 1], o01);
        o10 = fmaf(wgt, win[dh + 1][dw    ], o10);
        o11 = fmaf(wgt, win[dh + 1][dw + 1], o11);
      }
  }
  const float a2 = a2s[0], cc2 = c2s[0];
  float2 row0 = make_float2(fmaxf(fmaf(o00, a2, cc2), 0.f),
                            fmaxf(fmaf(o01, a2, cc2), 0.f));
  float2 row1 = make_float2(fmaxf(fmaf(o10, a2, cc2), 0.f),
                            fmaxf(fmaf(o11, a2, cc2), 0.f));
  const int sel = (fixed_proj < 0) ? proj : 0;
  float* ob = out + sel * 1048576 + b * 262144;
  *(float2*)&ob[(h0 + r0    ) * 512 + (w0 + c0)] = row0;
  *(float2*)&ob[(h0 + r0 + 1) * 512 + (w0 + c0)] = row1;
}

// ---------------------------------------------------------------------------
// Scores + softmax + attn write. Block = (b, i, j, 16-query tile).
// Scores held in registers (32/thread); K chunk staged transposed in LDS.
// ---------------------------------------------------------------------------
__global__ __launch_bounds__(256)
void attn_score_kernel(const float* __restrict__ Q, const float* __restrict__ K,
                       float* __restrict__ attn)
{
  __shared__ float qs[16][64];
  __shared__ float kt[64][128];
  const int t  = threadIdx.x;
  const int b  = blockIdx.z;
  const int ij = blockIdx.y;
  const int i  = ij >> 3, j = ij & 7;
  const int m0 = blockIdx.x * 16;

  {
    int m = t >> 4, d0 = (t & 15) * 4;
    float4 qv = *(const float4*)&Q[b * 262144 + (m0 + m) * 512 + i * 64 + d0];
    *(float4*)&qs[m][d0] = make_float4(qv.x * 0.125f, qv.y * 0.125f,
                                       qv.z * 0.125f, qv.w * 0.125f);
  }

  const int tm = t >> 5;   // 0..7: rows tm and tm+8
  const int tn = t & 31;   // 0..31: 4 cols each per chunk
  float S[4][8];

  #pragma unroll
  for (int c = 0; c < 4; ++c) {
    __syncthreads();
    {
      int n = t >> 1, d0 = (t & 1) * 32;
      const float* kp = &K[b * 262144 + (c * 128 + n) * 512 + j * 64 + d0];
      #pragma unroll
      for (int q4 = 0; q4 < 8; ++q4) {
        float4 kv = *(const float4*)&kp[q4 * 4];
        kt[d0 + q4 * 4 + 0][n] = kv.x;
        kt[d0 + q4 * 4 + 1][n] = kv.y;
        kt[d0 + q4 * 4 + 2][n] = kv.z;
        kt[d0 + q4 * 4 + 3][n] = kv.w;
      }
    }
    __syncthreads();
    float acc[8] = {0.f, 0.f, 0.f, 0.f, 0.f, 0.f, 0.f, 0.f};
    #pragma unroll 4
    for (int dd = 0; dd < 64; dd += 4) {
      float4 q0 = *(const float4*)&qs[tm    ][dd];
      float4 q1 = *(const float4*)&qs[tm + 8][dd];
      float4 k0 = *(const float4*)&kt[dd    ][tn * 4];
      float4 k1 = *(const float4*)&kt[dd + 1][tn * 4];
      float4 k2 = *(const float4*)&kt[dd + 2][tn * 4];
      float4 k3 = *(const float4*)&kt[dd + 3][tn * 4];
      acc[0] = fmaf(q0.x,k0.x, fmaf(q0.y,k1.x, fmaf(q0.z,k2.x, fmaf(q0.w,k3.x, acc[0]))));
      acc[1] = fmaf(q0.x,k0.y, fmaf(q0.y,k1.y, fmaf(q0.z,k2.y, fmaf(q0.w,k3.y, acc[1]))));
      acc[2] = fmaf(q0.x,k0.z, fmaf(q0.y,k1.z, fmaf(q0.z,k2.z, fmaf(q0.w,k3.z, acc[2]))));
      acc[3] = fmaf(q0.x,k0.w, fmaf(q0.y,k1.w, fmaf(q0.z,k2.w, fmaf(q0.w,k3.w, acc[3]))));
      acc[4] = fmaf(q1.x,k0.x, fmaf(q1.y,k1.x, fmaf(q1.z,k2.x, fmaf(q1.w,k3.x, acc[4]))));
      acc[5] = fmaf(q1.x,k0.y, fmaf(q1.y,k1.y, fmaf(q1.z,k2.y, fmaf(q1.w,k3.y, acc[5]))));
      acc[6] = fmaf(q1.x,k0.z, fmaf(q1.y,k1.z, fmaf(q1.z,k2.z, fmaf(q1.w,k3.z, acc[6]))));
      acc[7] = fmaf(q1.x,k0.w, fmaf(q1.y,k1.w, fmaf(q1.z,k2.w, fmaf(q1.w,k3.w, acc[7]))));
    }
    #pragma unroll
    for (int u = 0; u < 8; ++u) S[c][u] = acc[u];
  }

  // Softmax over n (512) per row, reduced across the 32-lane tn group.
  // (wave64: xor offsets 1..16 stay within each 32-lane half = the tn group)
  float* ap = attn + (size_t)((b * 8 + i) * 8 + j) * 262144;
  #pragma unroll
  for (int mm = 0; mm < 2; ++mm) {
    int m = tm + mm * 8;
    float mx = -3.0e38f;
    #pragma unroll
    for (int c = 0; c < 4; ++c)
      #pragma unroll
      for (int nn = 0; nn < 4; ++nn)
        mx = fmaxf(mx, S[c][mm * 4 + nn]);
    #pragma unroll
    for (int off = 1; off < 32; off <<= 1)
      mx = fmaxf(mx, __shfl_xor(mx, off));
    float sum = 0.f;
    #pragma unroll
    for (int c = 0; c < 4; ++c)
      #pragma unroll
      for (int nn = 0; nn < 4; ++nn) {
        float e = __expf(S[c][mm * 4 + nn] - mx);
        S[c][mm * 4 + nn] = e;
        sum += e;
      }
    #pragma unroll
    for (int off = 1; off < 32; off <<= 1)
      sum += __shfl_xor(sum, off);
    float rinv = 1.0f / sum;
    float* rowp = ap + (size_t)(m0 + m) * 512;
    #pragma unroll
    for (int c = 0; c < 4; ++c) {
      float4 o = make_float4(S[c][mm * 4 + 0] * rinv, S[c][mm * 4 + 1] * rinv,
                             S[c][mm * 4 + 2] * rinv, S[c][mm * 4 + 3] * rinv);
      *(float4*)&rowp[c * 128 + tn * 4] = o;
    }
  }
}

// ---------------------------------------------------------------------------
// ctx partial GEMM: C(128x64) = attn[b,i,j,m-tile,:] (128x512) @ V_j (512x64).
// j-split into 8 partial buffers; reduction fused into final conv's load.
// ---------------------------------------------------------------------------
__global__ __launch_bounds__(256)
void ctx_kernel(const float* __restrict__ attn, const float* __restrict__ V,
                float* __restrict__ ctxp)
{
  __shared__ float Pt[32][132];  // transposed P chunk, padded row (132)
  __shared__ float Vs[32][64];
  const int t  = threadIdx.x;
  const int m0 = blockIdx.x * 128;
  const int j  = blockIdx.y;
  const int b  = blockIdx.z >> 3;
  const int i  = blockIdx.z & 7;

  const float* ap = attn + (size_t)((b * 8 + i) * 8 + j) * 262144;
  const float* vp = V + b * 262144 + j * 64;

  const int tmg = t >> 4;  // 0..15 -> 8 rows each
  const int td  = t & 15;  // 0..15 -> 4 cols each
  float4 acc[8];
  #pragma unroll
  for (int r = 0; r < 8; ++r) acc[r] = make_float4(0.f, 0.f, 0.f, 0.f);

  for (int c = 0; c < 16; ++c) {
    __syncthreads();
    {
      int m = t >> 1, k0 = (t & 1) * 16;
      const float* pr = ap + (size_t)(m0 + m) * 512 + c * 32 + k0;
      #pragma unroll
      for (int q4 = 0; q4 < 4; ++q4) {
        float4 pv = *(const float4*)&pr[q4 * 4];
        Pt[k0 + q4 * 4 + 0][m] = pv.x;
        Pt[k0 + q4 * 4 + 1][m] = pv.y;
        Pt[k0 + q4 * 4 + 2][m] = pv.z;
        Pt[k0 + q4 * 4 + 3][m] = pv.w;
      }
    }
    #pragma unroll
    for (int u = 0; u < 2; ++u) {
      int idx = t + u * 256;
      int k = idx >> 4, f = idx & 15;
      *(float4*)&Vs[k][f * 4] = *(const float4*)&vp[(size_t)(c * 32 + k) * 512 + f * 4];
    }
    __syncthreads();
    #pragma unroll 8
    for (int k = 0; k < 32; ++k) {
      float4 pa = *(const float4*)&Pt[k][tmg * 8];
      float4 pb = *(const float4*)&Pt[k][tmg * 8 + 4];
      float4 vv = *(const float4*)&Vs[k][td * 4];
      fma4(acc[0], pa.x, vv);
      fma4(acc[1], pa.y, vv);
      fma4(acc[2], pa.z, vv);
      fma4(acc[3], pa.w, vv);
      fma4(acc[4], pb.x, vv);
      fma4(acc[5], pb.y, vv);
      fma4(acc[6], pb.z, vv);
      fma4(acc[7], pb.w, vv);
    }
  }
  float* op = ctxp + j * 1048576 + b * 262144 + i * 64 + td * 4;
  #pragma unroll
  for (int r = 0; r < 8; ++r) {
    *(float4*)&op[(size_t)(m0 + tmg * 8 + r) * 512] = acc[r];
  }
}

extern "C" void kernel_launch(void* const* d_in, const int* in_sizes, int n_in,
                              void* d_out, int out_size, void* d_ws, size_t ws_size,
                              hipStream_t stream)
{
  const float* X   = (const float*)d_in[0];
  // d_in[1] = valid_lens: unused by the reference computation.
  const float* w1  = (const float*)d_in[2];
  const float* b1  = (const float*)d_in[3];
  const float* g1  = (const float*)d_in[4];
  const float* be1 = (const float*)d_in[5];
  const float* m1  = (const float*)d_in[6];
  const float* v1  = (const float*)d_in[7];
  const float* w2  = (const float*)d_in[8];
  const float* b2  = (const float*)d_in[9];
  const float* g2  = (const float*)d_in[10];
  const float* be2 = (const float*)d_in[11];
  const float* m2  = (const float*)d_in[12];
  const float* v2  = (const float*)d_in[13];

  float* ws   = (float*)d_ws;
  float* Qb   = ws;                  // 1M floats
  float* Kb   = ws + 1048576;        // 1M
  float* Vb   = ws + 2097152;        // 1M
  float* ctxp = ws + 3145728;        // 8 x 1M partials
  float* outp = (float*)d_out;       // out: 1,048,576 floats
  float* attn = outp + 1048576;      // attn: 67,108,864 floats

  // Q,K,V projections (proj 0..2 x b 0..3 in grid.z).
  conv_proj_kernel<<<dim3(16, 16, 12), 256, 0, stream>>>(
      X, 1, ws, -1, w1, b1, g1, be1, m1, v1, w2, b2, g2, be2, m2, v2);

  // Scores + softmax + attn output.
  attn_score_kernel<<<dim3(32, 64, 4), 256, 0, stream>>>(Qb, Kb, attn);

  // ctx partials (j-split).
  ctx_kernel<<<dim3(4, 8, 32), 256, 0, stream>>>(attn, Vb, ctxp);

  // Output projection (sums the 8 ctx partials during input staging).
  conv_proj_kernel<<<dim3(16, 16, 4), 256, 0, stream>>>(
      ctxp, 8, outp, 3, w1, b1, g1, be1, m1, v1, w2, b2, g2, be2, m2, v2);
}